// Round 1
// baseline (475.387 us; speedup 1.0000x reference)
//
#include <hip/hip_runtime.h>

// HyenaFilter = implicit-filter MLP (tiny) + FFT convolution.
// fftconv with fft_size=16384 >= 2L is exactly causal linear conv:
//   y[b,d,t] = sum_{s<=t} k[d,s] x[b,d,t-s] + bias[d]*x[b,d,t]
// bias term folded into k[d,0]. Both batches packed into one complex FFT
// (linearity => no spectrum unpacking needed). DIF fwd / DIT inv, no bitrev.

#define DIMC  768
#define BANDS 16
#define FO    64
#define LSEQ  8192
#define NFFT  16384
#define PI_F  3.14159265358979323846f

__device__ __forceinline__ int swz(int i) { return i ^ ((i >> 6) & 15); }

// ---------- FFT building blocks (N=16384, 1024 threads, 16 pts/thread) ----
// Ownerships: A: j*1024+t | B: b*1024+j*64+w | C: c*64+j*4+r4 | D: t*16+j

template<int SHIFT, int SMAX, int SMIN>
__device__ __forceinline__ void fwd_stages(float2 (&r)[16], int base)
{
#pragma unroll
    for (int S = SMAX; S >= SMIN; S >>= 1) {
        const int s = S << SHIFT;
        const float scale = -PI_F / (float)s;
#pragma unroll
        for (int g = 0; g < 8; ++g) {
            const int j  = ((g & ~(S - 1)) << 1) | (g & (S - 1));
            const int jS = j + S;
            int wexp = (base + (j << SHIFT)) & (s - 1);
            float ang = scale * (float)wexp;
            float sn, cs;
            __sincosf(ang, &sn, &cs);
            float2 u = r[j], v = r[jS];
            r[j].x = u.x + v.x;
            r[j].y = u.y + v.y;
            float dx = u.x - v.x;
            float dy = u.y - v.y;
            r[jS].x = dx * cs - dy * sn;
            r[jS].y = dx * sn + dy * cs;
        }
    }
}

template<int SHIFT, int SMIN, int SMAX>
__device__ __forceinline__ void inv_stages(float2 (&r)[16], int base)
{
#pragma unroll
    for (int S = SMIN; S <= SMAX; S <<= 1) {
        const int s = S << SHIFT;
        const float scale = PI_F / (float)s;   // conj twiddle
#pragma unroll
        for (int g = 0; g < 8; ++g) {
            const int j  = ((g & ~(S - 1)) << 1) | (g & (S - 1));
            const int jS = j + S;
            int wexp = (base + (j << SHIFT)) & (s - 1);
            float ang = scale * (float)wexp;
            float sn, cs;
            __sincosf(ang, &sn, &cs);
            float2 u = r[j], v = r[jS];
            float vx = v.x * cs - v.y * sn;
            float vy = v.x * sn + v.y * cs;
            r[j].x  = u.x + vx;
            r[j].y  = u.y + vy;
            r[jS].x = u.x - vx;
            r[jS].y = u.y - vy;
        }
    }
}

__device__ __forceinline__ void xchg(float2 (&r)[16], float2* lds,
                                     int baseW, int shiftW, int baseR, int shiftR)
{
    __syncthreads();   // protect previous reads of lds (WAR)
#pragma unroll
    for (int j = 0; j < 16; ++j) lds[swz(baseW + (j << shiftW))] = r[j];
    __syncthreads();
#pragma unroll
    for (int j = 0; j < 16; ++j) r[j] = lds[swz(baseR + (j << shiftR))];
}

__device__ __forceinline__ void fft_fwd(float2 (&r)[16], float2* lds, int t)
{
    const int bA = t;
    const int bB = ((t >> 6) << 10) | (t & 63);
    const int bC = ((t >> 2) << 6) | (t & 3);
    const int bD = t << 4;
    fwd_stages<10, 8, 1>(r, bA);        // s = 8192..1024
    xchg(r, lds, bA, 10, bB, 6);
    fwd_stages<6, 8, 1>(r, bB);         // s = 512..64
    xchg(r, lds, bB, 6, bC, 2);
    fwd_stages<2, 8, 1>(r, bC);         // s = 32..4
    xchg(r, lds, bC, 2, bD, 0);
    fwd_stages<0, 2, 1>(r, bD);         // s = 2,1
}

__device__ __forceinline__ void fft_inv(float2 (&r)[16], float2* lds, int t)
{
    const int bA = t;
    const int bB = ((t >> 6) << 10) | (t & 63);
    const int bC = ((t >> 2) << 6) | (t & 3);
    const int bD = t << 4;
    inv_stages<0, 1, 8>(r, bD);         // s = 1..8
    xchg(r, lds, bD, 0, bC, 2);
    inv_stages<2, 4, 8>(r, bC);         // s = 16,32
    xchg(r, lds, bC, 2, bB, 6);
    inv_stages<6, 1, 8>(r, bB);         // s = 64..512
    xchg(r, lds, bB, 6, bA, 10);
    inv_stages<10, 1, 8>(r, bA);        // s = 1024..8192
}

// ---------- Kernel 1: MLP hidden states h2[FO][LSEQ] ----------------------
// One wave per position; lane = hidden feature; __shfl for 64-dots.
__global__ void hidden_kernel(const float* __restrict__ W0, const float* __restrict__ b0,
                              const float* __restrict__ W1, const float* __restrict__ b1,
                              const float* __restrict__ W2, const float* __restrict__ b2,
                              const float* __restrict__ freq, float* __restrict__ hws)
{
    const int lane = threadIdx.x & 63;
    const int p = blockIdx.x * (blockDim.x >> 6) + (threadIdx.x >> 6);
    if (p >= LSEQ) return;
    const float tt = (float)p / (float)(LSEQ - 1);
    const float w  = 6.283185307179586f * (float)p / (float)LSEQ;

    // layer 0: z = [t, cos(f*w), -sin(f*w)]
    float acc = b0[lane] + tt * W0[lane];
#pragma unroll
    for (int j = 0; j < BANDS; ++j) {
        float f = 1e-4f + (float)j * ((15.0f - 1e-4f) / 15.0f);
        float a = f * w;
        acc += cosf(a)  * W0[(1 + j) * FO + lane];
        acc += -sinf(a) * W0[(1 + BANDS + j) * FO + lane];
    }
    float h = sinf(freq[lane] * acc);

    acc = b1[lane];
#pragma unroll
    for (int e = 0; e < FO; ++e) acc += __shfl(h, e) * W1[e * FO + lane];
    float h1 = sinf(freq[lane] * acc);

    acc = b2[lane];
#pragma unroll
    for (int e = 0; e < FO; ++e) acc += __shfl(h1, e) * W2[e * FO + lane];
    float h2 = sinf(freq[lane] * acc);

    hws[lane * LSEQ + p] = h2;    // feature-major, coalesced
}

// ---------- Kernel 2: k[d][p] = (h2 . Wf) * (exp(-t|delta|)+0.05) ---------
#define DCHUNK 96
__global__ void filter_kernel(const float* __restrict__ hws, const float* __restrict__ Wf,
                              float* __restrict__ kws)
{
    const int p  = blockIdx.x * 256 + threadIdx.x;
    const int d0 = blockIdx.y * DCHUNK;
    float h[FO];
#pragma unroll
    for (int j = 0; j < FO; ++j) h[j] = hws[j * LSEQ + p];
    const float tt = (float)p / (float)(LSEQ - 1);
    const float min_decay = -3.0701134573253937f;   // ln(0.01)/1.5
    const float max_decay = -15.350567286626971f;   // ln(0.01)/0.3
    for (int dd = 0; dd < DCHUNK; ++dd) {
        const int d = d0 + dd;
        float acc = 0.f;
#pragma unroll
        for (int j = 0; j < FO; ++j) acc += h[j] * Wf[j * DIMC + d];
        float delta = min_decay + (max_decay - min_decay) * ((float)d / (float)(DIMC - 1));
        float dec = expf(-tt * fabsf(delta));
        kws[(size_t)d * LSEQ + p] = acc * (dec + 0.05f);
    }
}

// ---------- Kernel 3: FFT convolution, one block per channel --------------
__global__ __launch_bounds__(1024) void conv_kernel(
    const float* __restrict__ x, const float* __restrict__ kf,
    const float* __restrict__ bias, float* __restrict__ out)
{
    __shared__ float2 lds[NFFT];         // 128 KB
    const int d = blockIdx.x;
    const int t = threadIdx.x;
    float2 r[16], kreg[16];

    // --- FFT of k (real, bias delta folded in) ---
    const float* krow = kf + (size_t)d * LSEQ;
#pragma unroll
    for (int j = 0; j < 8; ++j) { r[j].x = krow[(j << 10) + t]; r[j].y = 0.f; }
#pragma unroll
    for (int j = 8; j < 16; ++j) { r[j].x = 0.f; r[j].y = 0.f; }
    if (t == 0) r[0].x += bias[d];
    fft_fwd(r, lds, t);
    const float invn = 1.0f / (float)NFFT;
#pragma unroll
    for (int j = 0; j < 16; ++j) { kreg[j].x = r[j].x * invn; kreg[j].y = r[j].y * invn; }

    // --- FFT of packed x0 + i*x1 ---
    const float* x0 = x + (size_t)d * LSEQ;
    const float* x1 = x + (size_t)(DIMC + d) * LSEQ;
#pragma unroll
    for (int j = 0; j < 8; ++j) { int n = (j << 10) + t; r[j].x = x0[n]; r[j].y = x1[n]; }
#pragma unroll
    for (int j = 8; j < 16; ++j) { r[j].x = 0.f; r[j].y = 0.f; }
    fft_fwd(r, lds, t);

    // --- pointwise multiply (scrambled orders align) ---
#pragma unroll
    for (int j = 0; j < 16; ++j) {
        float ax = r[j].x, ay = r[j].y;
        float bx = kreg[j].x, by = kreg[j].y;
        r[j].x = ax * bx - ay * by;
        r[j].y = ax * by + ay * bx;
    }

    // --- inverse FFT -> y0 + i*y1, natural order ---
    fft_inv(r, lds, t);

    float* o0 = out + (size_t)d * LSEQ;
    float* o1 = out + (size_t)(DIMC + d) * LSEQ;
#pragma unroll
    for (int j = 0; j < 8; ++j) { int n = (j << 10) + t; o0[n] = r[j].x; o1[n] = r[j].y; }
}

extern "C" void kernel_launch(void* const* d_in, const int* in_sizes, int n_in,
                              void* d_out, int out_size, void* d_ws, size_t ws_size,
                              hipStream_t stream)
{
    (void)in_sizes; (void)n_in; (void)out_size; (void)d_ws; (void)ws_size;
    const float* x    = (const float*)d_in[0];
    const float* W0   = (const float*)d_in[1];
    const float* b0   = (const float*)d_in[2];
    const float* W1   = (const float*)d_in[3];
    const float* b1   = (const float*)d_in[4];
    const float* W2   = (const float*)d_in[5];
    const float* b2   = (const float*)d_in[6];
    const float* Wf   = (const float*)d_in[7];
    const float* freq = (const float*)d_in[8];
    const float* bias = (const float*)d_in[9];
    float* out = (float*)d_out;

    // Stage scratch inside d_out (no reliance on ws_size):
    //   hws = out[0 .. 64*8192)            (batch-0 low channels, rewritten later)
    //   kws = out + 768*8192               (batch-1 half; conv block d reads its
    //                                       own k row fully before writing y1 there)
    float* hws = out;
    float* kws = out + (size_t)DIMC * LSEQ;

    hipLaunchKernelGGL(hidden_kernel, dim3(LSEQ / 4), dim3(256), 0, stream,
                       W0, b0, W1, b1, W2, b2, freq, hws);
    hipLaunchKernelGGL(filter_kernel, dim3(LSEQ / 256, DIMC / DCHUNK), dim3(256), 0, stream,
                       hws, Wf, kws);
    hipLaunchKernelGGL(conv_kernel, dim3(DIMC), dim3(1024), 0, stream,
                       x, kws, bias, out);
}

// Round 2
// 407.510 us; speedup vs baseline: 1.1666x; 1.1666x over previous
//
#include <hip/hip_runtime.h>

// HyenaFilter = implicit-filter MLP (tiny) + FFT convolution.
// fftconv with fft_size=16384 >= 2L is exactly causal linear conv:
//   y[b,d,t] = sum_{s<=t} k[d,s] x[b,d,t-s] + bias[d]*x[b,d,t]
// bias term folded into k[d,0]. Both batches packed into one complex FFT
// (linearity => no spectrum unpacking needed). DIF fwd / DIT inv, no bitrev.
// R2: __launch_bounds__(1024,4) to unlock 128 VGPRs (R1 spilled at 64);
//     zero-padded first fwd stage + truncated last inv stage specialized.

#define DIMC  768
#define BANDS 16
#define FO    64
#define LSEQ  8192
#define NFFT  16384
#define PI_F  3.14159265358979323846f

__device__ __forceinline__ int swz(int i) { return i ^ ((i >> 6) & 15); }

// ---------- FFT building blocks (N=16384, 1024 threads, 16 pts/thread) ----
// Ownerships: A: j*1024+t | B: b*1024+j*64+w | C: c*64+j*4+r4 | D: t*16+j

template<int SHIFT, int SMAX, int SMIN>
__device__ __forceinline__ void fwd_stages(float2 (&r)[16], int base)
{
#pragma unroll
    for (int S = SMAX; S >= SMIN; S >>= 1) {
        const int s = S << SHIFT;
        const float scale = -PI_F / (float)s;
#pragma unroll
        for (int g = 0; g < 8; ++g) {
            const int j  = ((g & ~(S - 1)) << 1) | (g & (S - 1));
            const int jS = j + S;
            int wexp = (base + (j << SHIFT)) & (s - 1);
            float ang = scale * (float)wexp;
            float sn, cs;
            __sincosf(ang, &sn, &cs);
            float2 u = r[j], v = r[jS];
            r[j].x = u.x + v.x;
            r[j].y = u.y + v.y;
            float dx = u.x - v.x;
            float dy = u.y - v.y;
            r[jS].x = dx * cs - dy * sn;
            r[jS].y = dx * sn + dy * cs;
        }
    }
}

template<int SHIFT, int SMIN, int SMAX>
__device__ __forceinline__ void inv_stages(float2 (&r)[16], int base)
{
#pragma unroll
    for (int S = SMIN; S <= SMAX; S <<= 1) {
        const int s = S << SHIFT;
        const float scale = PI_F / (float)s;   // conj twiddle
#pragma unroll
        for (int g = 0; g < 8; ++g) {
            const int j  = ((g & ~(S - 1)) << 1) | (g & (S - 1));
            const int jS = j + S;
            int wexp = (base + (j << SHIFT)) & (s - 1);
            float ang = scale * (float)wexp;
            float sn, cs;
            __sincosf(ang, &sn, &cs);
            float2 u = r[j], v = r[jS];
            float vx = v.x * cs - v.y * sn;
            float vy = v.x * sn + v.y * cs;
            r[j].x  = u.x + vx;
            r[j].y  = u.y + vy;
            r[jS].x = u.x - vx;
            r[jS].y = u.y - vy;
        }
    }
}

__device__ __forceinline__ void xchg(float2 (&r)[16], float2* lds,
                                     int baseW, int shiftW, int baseR, int shiftR)
{
    __syncthreads();   // protect previous reads of lds (WAR)
#pragma unroll
    for (int j = 0; j < 16; ++j) lds[swz(baseW + (j << shiftW))] = r[j];
    __syncthreads();
#pragma unroll
    for (int j = 0; j < 16; ++j) r[j] = lds[swz(baseR + (j << shiftR))];
}

// Forward FFT, input zero-padded: only r[0..7] valid on entry (upper half =0).
__device__ __forceinline__ void fft_fwd_zp(float2 (&r)[16], float2* lds, int t)
{
    const int bA = t;
    const int bB = ((t >> 6) << 10) | (t & 63);
    const int bC = ((t >> 2) << 6) | (t & 3);
    const int bD = t << 4;
    // stage s=8192 with v=0: out_lo = u, out_hi = u * w
    const float sc0 = -PI_F / 8192.0f;
#pragma unroll
    for (int j = 0; j < 8; ++j) {
        float ang = sc0 * (float)(t + (j << 10));
        float sn, cs;
        __sincosf(ang, &sn, &cs);
        float2 u = r[j];
        r[j + 8].x = u.x * cs - u.y * sn;
        r[j + 8].y = u.x * sn + u.y * cs;
    }
    fwd_stages<10, 4, 1>(r, bA);        // s = 4096..1024
    xchg(r, lds, bA, 10, bB, 6);
    fwd_stages<6, 8, 1>(r, bB);         // s = 512..64
    xchg(r, lds, bB, 6, bC, 2);
    fwd_stages<2, 8, 1>(r, bC);         // s = 32..4
    xchg(r, lds, bC, 2, bD, 0);
    fwd_stages<0, 2, 1>(r, bD);         // s = 2,1
}

// Inverse FFT; only outputs n < 8192 (r[0..7], A-ownership) are produced.
__device__ __forceinline__ void fft_inv(float2 (&r)[16], float2* lds, int t)
{
    const int bA = t;
    const int bB = ((t >> 6) << 10) | (t & 63);
    const int bC = ((t >> 2) << 6) | (t & 3);
    const int bD = t << 4;
    inv_stages<0, 1, 8>(r, bD);         // s = 1..8
    xchg(r, lds, bD, 0, bC, 2);
    inv_stages<2, 4, 8>(r, bC);         // s = 16,32
    xchg(r, lds, bC, 2, bB, 6);
    inv_stages<6, 1, 8>(r, bB);         // s = 64..512
    xchg(r, lds, bB, 6, bA, 10);
    inv_stages<10, 1, 4>(r, bA);        // s = 1024..4096
    // final stage s=8192: keep only lower outputs  y = u + w*v
    const float scF = PI_F / 8192.0f;
#pragma unroll
    for (int j = 0; j < 8; ++j) {
        float ang = scF * (float)(t + (j << 10));
        float sn, cs;
        __sincosf(ang, &sn, &cs);
        float2 u = r[j], v = r[j + 8];
        r[j].x = u.x + (v.x * cs - v.y * sn);
        r[j].y = u.y + (v.x * sn + v.y * cs);
    }
}

// ---------- Kernel 1: MLP hidden states h2[FO][LSEQ] ----------------------
// One wave per position; lane = hidden feature; __shfl for 64-dots.
__global__ void hidden_kernel(const float* __restrict__ W0, const float* __restrict__ b0,
                              const float* __restrict__ W1, const float* __restrict__ b1,
                              const float* __restrict__ W2, const float* __restrict__ b2,
                              const float* __restrict__ freq, float* __restrict__ hws)
{
    const int lane = threadIdx.x & 63;
    const int p = blockIdx.x * (blockDim.x >> 6) + (threadIdx.x >> 6);
    if (p >= LSEQ) return;
    const float tt = (float)p / (float)(LSEQ - 1);
    const float w  = 6.283185307179586f * (float)p / (float)LSEQ;

    // layer 0: z = [t, cos(f*w), -sin(f*w)]
    float acc = b0[lane] + tt * W0[lane];
#pragma unroll
    for (int j = 0; j < BANDS; ++j) {
        float f = 1e-4f + (float)j * ((15.0f - 1e-4f) / 15.0f);
        float a = f * w;
        float sn, cs;
        __sincosf(a, &sn, &cs);
        acc += cs  * W0[(1 + j) * FO + lane];
        acc += -sn * W0[(1 + BANDS + j) * FO + lane];
    }
    float h = __sinf(freq[lane] * acc);

    acc = b1[lane];
#pragma unroll
    for (int e = 0; e < FO; ++e) acc += __shfl(h, e) * W1[e * FO + lane];
    float h1 = __sinf(freq[lane] * acc);

    acc = b2[lane];
#pragma unroll
    for (int e = 0; e < FO; ++e) acc += __shfl(h1, e) * W2[e * FO + lane];
    float h2 = __sinf(freq[lane] * acc);

    hws[lane * LSEQ + p] = h2;    // feature-major, coalesced
}

// ---------- Kernel 2: k[d][p] = (h2 . Wf) * (exp(-t|delta|)+0.05) ---------
#define DCHUNK 96
__global__ __launch_bounds__(256, 4) void filter_kernel(
    const float* __restrict__ hws, const float* __restrict__ Wf,
    float* __restrict__ kws)
{
    const int p  = blockIdx.x * 256 + threadIdx.x;
    const int d0 = blockIdx.y * DCHUNK;
    float h[FO];
#pragma unroll
    for (int j = 0; j < FO; ++j) h[j] = hws[j * LSEQ + p];
    const float tt = (float)p / (float)(LSEQ - 1);
    const float min_decay = -3.0701134573253937f;   // ln(0.01)/1.5
    const float max_decay = -15.350567286626971f;   // ln(0.01)/0.3
    for (int dd = 0; dd < DCHUNK; ++dd) {
        const int d = d0 + dd;
        float acc = 0.f;
#pragma unroll
        for (int j = 0; j < FO; ++j) acc += h[j] * Wf[j * DIMC + d];
        float delta = min_decay + (max_decay - min_decay) * ((float)d / (float)(DIMC - 1));
        float dec = __expf(-tt * fabsf(delta));
        kws[(size_t)d * LSEQ + p] = acc * (dec + 0.05f);
    }
}

// ---------- Kernel 3: FFT convolution, one block per channel --------------
__global__ __launch_bounds__(1024, 4) void conv_kernel(
    const float* __restrict__ x, const float* __restrict__ kf,
    const float* __restrict__ bias, float* __restrict__ out)
{
    __shared__ float2 lds[NFFT];         // 128 KB
    const int d = blockIdx.x;
    const int t = threadIdx.x;
    float2 r[16], kreg[16];

    // --- FFT of k (real, zero-padded; bias delta folded in) ---
    const float* krow = kf + (size_t)d * LSEQ;
#pragma unroll
    for (int j = 0; j < 8; ++j) { r[j].x = krow[(j << 10) + t]; r[j].y = 0.f; }
    if (t == 0) r[0].x += bias[d];
    fft_fwd_zp(r, lds, t);
    const float invn = 1.0f / (float)NFFT;
#pragma unroll
    for (int j = 0; j < 16; ++j) { kreg[j].x = r[j].x * invn; kreg[j].y = r[j].y * invn; }

    // --- FFT of packed x0 + i*x1 (zero-padded) ---
    const float* x0 = x + (size_t)d * LSEQ;
    const float* x1 = x + (size_t)(DIMC + d) * LSEQ;
#pragma unroll
    for (int j = 0; j < 8; ++j) { int n = (j << 10) + t; r[j].x = x0[n]; r[j].y = x1[n]; }
    fft_fwd_zp(r, lds, t);

    // --- pointwise multiply (scrambled orders align) ---
#pragma unroll
    for (int j = 0; j < 16; ++j) {
        float ax = r[j].x, ay = r[j].y;
        float bx = kreg[j].x, by = kreg[j].y;
        r[j].x = ax * bx - ay * by;
        r[j].y = ax * by + ay * bx;
    }

    // --- inverse FFT -> y0 + i*y1, natural order, first 8192 only ---
    fft_inv(r, lds, t);

    float* o0 = out + (size_t)d * LSEQ;
    float* o1 = out + (size_t)(DIMC + d) * LSEQ;
#pragma unroll
    for (int j = 0; j < 8; ++j) { int n = (j << 10) + t; o0[n] = r[j].x; o1[n] = r[j].y; }
}

extern "C" void kernel_launch(void* const* d_in, const int* in_sizes, int n_in,
                              void* d_out, int out_size, void* d_ws, size_t ws_size,
                              hipStream_t stream)
{
    (void)in_sizes; (void)n_in; (void)out_size; (void)d_ws; (void)ws_size;
    const float* x    = (const float*)d_in[0];
    const float* W0   = (const float*)d_in[1];
    const float* b0   = (const float*)d_in[2];
    const float* W1   = (const float*)d_in[3];
    const float* b1   = (const float*)d_in[4];
    const float* W2   = (const float*)d_in[5];
    const float* b2   = (const float*)d_in[6];
    const float* Wf   = (const float*)d_in[7];
    const float* freq = (const float*)d_in[8];
    const float* bias = (const float*)d_in[9];
    float* out = (float*)d_out;

    // Stage scratch inside d_out (no reliance on ws_size):
    //   hws = out[0 .. 64*8192)            (batch-0 low channels, rewritten later)
    //   kws = out + 768*8192               (batch-1 half; conv block d reads its
    //                                       own k row fully before writing y1 there)
    float* hws = out;
    float* kws = out + (size_t)DIMC * LSEQ;

    hipLaunchKernelGGL(hidden_kernel, dim3(LSEQ / 4), dim3(256), 0, stream,
                       W0, b0, W1, b1, W2, b2, freq, hws);
    hipLaunchKernelGGL(filter_kernel, dim3(LSEQ / 256, DIMC / DCHUNK), dim3(256), 0, stream,
                       hws, Wf, kws);
    hipLaunchKernelGGL(conv_kernel, dim3(DIMC), dim3(1024), 0, stream,
                       x, kws, bias, out);
}